// Round 19
// baseline (477.152 us; speedup 1.0000x reference)
//
#include <hip/hip_runtime.h>
#include <stdint.h>

typedef unsigned short u16;
typedef __attribute__((ext_vector_type(8))) short short8;
typedef __attribute__((ext_vector_type(4))) float f32x4;

#define NB 32
#define PP 1024
#define SEQ 128
#define EE 768
#define HH 8
#define DD 96
#define NCC 5
#define NLL 3

__device__ __forceinline__ float bf2f(u16 x){ unsigned u=((unsigned)x)<<16; float f; __builtin_memcpy(&f,&u,4); return f; }
__device__ __forceinline__ u16 f2bf(float f){ unsigned u; __builtin_memcpy(&u,&f,4); u=(u+0x7FFFu+((u>>16)&1u))>>16; return (u16)u; }

__device__ __forceinline__ short8 cvt8(const float* p) {
  f32x4 a = *(const f32x4*)p;
  f32x4 b = *(const f32x4*)(p+4);
  short8 r;
  r[0]=(short)f2bf(a[0]); r[1]=(short)f2bf(a[1]); r[2]=(short)f2bf(a[2]); r[3]=(short)f2bf(a[3]);
  r[4]=(short)f2bf(b[0]); r[5]=(short)f2bf(b[1]); r[6]=(short)f2bf(b[2]); r[7]=(short)f2bf(b[3]);
  return r;
}

__device__ __forceinline__ void gl16(const u16* g, u16* l) {
  __builtin_amdgcn_global_load_lds((const __attribute__((address_space(1))) void*)g,
                                   (__attribute__((address_space(3))) void*)l, 16, 0, 0);
}

// head-major A address: element (row fixed in aBase, k) of Q'[b][h][1024][96]
__device__ __forceinline__ const u16* ah_addr(const u16* aBase, int k0) {
  const int h = k0/96;
  return aBase + (size_t)h*98304 + (k0 - h*96);
}

// ---------------- fused f32 -> bf16 bulk convert (4 segments, 1 launch) -----
__global__ __launch_bounds__(256) void k_cvt4(
    const float* __restrict__ s0, u16* __restrict__ d0, int c0,
    const float* __restrict__ s1, u16* __restrict__ d1, int c1,
    const float* __restrict__ s2, u16* __restrict__ d2, int c2,
    const float* __restrict__ s3, u16* __restrict__ d3, int c3)
{
  int i = blockIdx.x*256 + threadIdx.x;
  const int stride = gridDim.x*256;
  const int tot = c0+c1+c2+c3;
  for (; i < tot; i += stride) {
    int j = i; const float* s; u16* d;
    if (j < c0) { s=s0; d=d0; }
    else { j-=c0; if (j<c1){s=s1;d=d1;}
      else { j-=c1; if (j<c2){s=s2;d=d2;} else { j-=c2; s=s3; d=d3; } } }
    *(short8*)(d + (size_t)j*8) = cvt8(s + (size_t)j*8);
  }
}

__global__ __launch_bounds__(256) void k_cvt(const float* __restrict__ s, u16* __restrict__ d, int n8) {
  int i = blockIdx.x*256 + threadIdx.x;
  const int stride = gridDim.x*256;
  for (; i < n8; i += stride) *(short8*)(d + (size_t)i*8) = cvt8(s + (size_t)i*8);
}

// ---------------- block LN stats helper (256 threads, 3 vals/thread) --------
__device__ __forceinline__ void ln_stats(float v0, float v1, float v2, float* red, int t,
                                         float& mean, float& rstd) {
  float ps = v0+v1+v2;
  float ps2 = v0*v0+v1*v1+v2*v2;
  #pragma unroll
  for (int o=32;o;o>>=1){ ps += __shfl_down(ps,o,64); ps2 += __shfl_down(ps2,o,64); }
  if ((t&63)==0){ red[t>>6]=ps; red[4+(t>>6)]=ps2; }
  __syncthreads();
  mean = (red[0]+red[1]+red[2]+red[3])*(1.0f/EE);
  float var = (red[4]+red[5]+red[6]+red[7])*(1.0f/EE) - mean*mean;
  rstd = rsqrtf(var + 1e-5f);
  __syncthreads();
}

// ---------------- big GEMM: 256x128 tile, 2-deep counted-vmcnt pipeline -----
// 4 waves; wave w owns rows w*64..w*64+63 of the 256-row tile, all 128 cols.
// 32 MFMA per K-step per wave vs 2 barriers (2x the old amortization).
// LDS 48KB: A 4x64-row chunks (16KB) + B 2 chunks (8KB), double-buffered.
// 6 gl16 per tile-step -> counted s_waitcnt vmcnt(6) in steady state.
template<int EPI, int AH>
__global__ __launch_bounds__(256) void gemm_bt(const u16* __restrict__ A, const u16* __restrict__ Bw,
        const float* __restrict__ bias, const u16* __restrict__ Res,
        u16* __restrict__ C, float* __restrict__ Cf, u16* __restrict__ C2,
        int M, int N, int K, int NTB)
{
  __shared__ u16 As[2][8192];
  __shared__ u16 Bs[2][4096];
  const int nwg = gridDim.x;
  const int bid = blockIdx.x;
  const int task = (bid & 7)*(nwg >> 3) + (bid >> 3);
  const int m0 = (task / NTB)*256, n0 = (task % NTB)*128;
  const int t = threadIdx.x;
  const int lane = t&63, w = t>>6, lm = lane&15, lg = lane>>4;
  const int o   = w*1024 + lane*16;
  const int srow = o>>6;
  const int sg   = ((o>>4)&3) ^ ((srow>>1)&3);
  const int row0 = m0 + srow;
  const u16* ag    = A + (size_t)row0*K + sg*8;                       // AH=0
  const u16* aBase = A + (size_t)((row0>>10)*8)*98304                  // AH=1
                       + (size_t)(row0&1023)*96 + sg*8;
  const u16* bg = Bw + (size_t)(n0+srow)*K + sg*8;
  const size_t rstepA = (size_t)64*K;     // +64 rows (row-major)
  const size_t rstepH = 6144;             // +64 rows head-major (64*96)
  const int s  = (lm>>1)&3;
  const int ra = (w*64+lm)*32 + (lg^s)*8;
  const int rb = lm*32 + (lg^s)*8;
  const int NT = K>>5;

  f32x4 acc[4][8] = {};
  #pragma unroll
  for (int p=0;p<2;p++) {
    const int k0 = p<<5;
    if constexpr (AH) {
      const u16* pa = ah_addr(aBase, k0);
      #pragma unroll
      for (int c=0;c<4;c++) gl16(pa + (size_t)c*rstepH, &As[p][c*2048 + w*512]);
    } else {
      #pragma unroll
      for (int c=0;c<4;c++) gl16(ag + k0 + (size_t)c*rstepA, &As[p][c*2048 + w*512]);
    }
    #pragma unroll
    for (int c=0;c<2;c++) gl16(bg + k0 + (size_t)c*rstepA, &Bs[p][c*2048 + w*512]);
  }
  int cur = 0;
  for (int kt=0; kt<NT; ++kt) {
    if (kt+1 < NT) { asm volatile("s_waitcnt vmcnt(6)" ::: "memory"); }
    else           { asm volatile("s_waitcnt vmcnt(0)" ::: "memory"); }
    __builtin_amdgcn_sched_barrier(0);
    __builtin_amdgcn_s_barrier();          // tile kt visible to all waves
    short8 af[4], bf[8];
    #pragma unroll
    for (int mi=0;mi<4;mi++) af[mi] = *(const short8*)&As[cur][ra + mi*512];
    #pragma unroll
    for (int ni=0;ni<8;ni++) bf[ni] = *(const short8*)&Bs[cur][rb + ni*512];
    asm volatile("s_waitcnt lgkmcnt(0)" ::: "memory");  // frags in regs
    __builtin_amdgcn_sched_barrier(0);
    __builtin_amdgcn_s_barrier();          // all waves done reading buf cur
    if (kt+2 < NT) {                       // refill freed buffer (tile kt+2)
      const int k0 = (kt+2)<<5;
      if constexpr (AH) {
        const u16* pa = ah_addr(aBase, k0);
        #pragma unroll
        for (int c=0;c<4;c++) gl16(pa + (size_t)c*rstepH, &As[cur][c*2048 + w*512]);
      } else {
        #pragma unroll
        for (int c=0;c<4;c++) gl16(ag + k0 + (size_t)c*rstepA, &As[cur][c*2048 + w*512]);
      }
      #pragma unroll
      for (int c=0;c<2;c++) gl16(bg + k0 + (size_t)c*rstepA, &Bs[cur][c*2048 + w*512]);
    }
    #pragma unroll
    for (int mi=0;mi<4;mi++)
      #pragma unroll
      for (int ni=0;ni<8;ni++)
        acc[mi][ni] = __builtin_amdgcn_mfma_f32_16x16x32_bf16(af[mi], bf[ni], acc[mi][ni], 0,0,0);
    cur ^= 1;
  }
  #pragma unroll
  for (int mi=0;mi<4;mi++) {
    #pragma unroll
    for (int ni=0;ni<8;ni++) {
      const int col = n0 + ni*16 + lm;
      const float bv = bias[col];
      const int hq = (n0 + ni*16)/96;       // head idx (16-col groups never cross)
      const int dq = col - hq*96;
      #pragma unroll
      for (int r=0;r<4;r++) {
        const int row = m0 + w*64 + mi*16 + lg*4 + r;
        float v = acc[mi][ni][r] + bv;
        if constexpr (EPI==1) v += bf2f(Res[(size_t)row*N + col]);
        if constexpr (EPI==3) {
          Cf[(size_t)row*N + col] = v;
        } else if constexpr (EPI==2) {
          if (col < EE) C[(size_t)row*EE + col] = f2bf(v);
          else C2[((size_t)(row>>7)*EE + (col-EE))*SEQ + (row&127)] = f2bf(v);
        } else if constexpr (EPI==4) {
          C[((size_t)((row>>10)*8 + hq)*1024 + (row&1023))*96 + dq] = f2bf(v);
        } else {
          C[(size_t)row*N + col] = f2bf(v);
        }
      }
    }
  }
}

// ---------------- task GEMM: split-K partials, no barriers, no LDS ----------
template<int MT, int AF>
__global__ __launch_bounds__(256) void gemm_tk(const void* __restrict__ Av, const float* __restrict__ W,
    float* __restrict__ Ppart, int ngroups, int KS, int K, int lda, long strideA, long strideW)
{
  const int task = blockIdx.x;
  const int nt = task % 6;
  const int g  = (task/6) % ngroups;
  const int ks = task/(6*ngroups);
  const int t = threadIdx.x, l = t&63, w = t>>6, lm = l&15, lg = l>>4;
  const int slice = K/KS, kbase = ks*slice;
  const int n0 = nt*128 + w*32;
  W += (size_t)g*strideW;
  f32x4 acc[MT/16][2] = {};
  for (int ki=0; ki<slice; ki+=32) {
    const int k0 = kbase + ki;
    short8 af[MT/16];
    #pragma unroll
    for (int m=0;m<MT/16;m++) {
      if constexpr (AF) af[m] = cvt8((const float*)Av + (size_t)g*strideA + (size_t)(m*16+lm)*lda + k0 + lg*8);
      else af[m] = *(const short8*)((const u16*)Av + (size_t)g*strideA + (size_t)(m*16+lm)*lda + k0 + lg*8);
    }
    #pragma unroll
    for (int ni=0;ni<2;ni++) {
      const short8 bf = cvt8(W + (size_t)(n0+ni*16+lm)*K + k0 + lg*8);
      #pragma unroll
      for (int m=0;m<MT/16;m++)
        acc[m][ni] = __builtin_amdgcn_mfma_f32_16x16x32_bf16(af[m], bf, acc[m][ni], 0,0,0);
    }
  }
  float* pb = Ppart + (size_t)(ks*ngroups+g)*MT*768;
  #pragma unroll
  for (int m=0;m<MT/16;m++)
    #pragma unroll
    for (int ni=0;ni<2;ni++)
      #pragma unroll
      for (int r=0;r<4;r++)
        pb[(size_t)(m*16+lg*4+r)*768 + n0+ni*16+lm] = acc[m][ni][r];
}

// ---------------- reduce partials + bias (+LN+relu variant) ------------------
__global__ __launch_bounds__(256) void k_red(const float* __restrict__ Ppart,
    float* __restrict__ outF, u16* __restrict__ outB,
    const float* __restrict__ bias, long strideB,
    int MT, int ngroups, int KS, int Mreal, long strideR, long strideG)
{
  const int bid = blockIdx.x, g = bid/Mreal, rr = bid%Mreal, t = threadIdx.x;
  #pragma unroll
  for (int i=0;i<3;i++) {
    const int e = t + i*256;
    float s = bias[(size_t)g*strideB + e];
    for (int ks=0; ks<KS; ++ks) s += Ppart[((size_t)(ks*ngroups+g)*MT + rr)*768 + e];
    const size_t off = (size_t)rr*strideR + (size_t)g*strideG + e;
    if (outF) outF[off] = s;
    if (outB) outB[off] = f2bf(s);
  }
}

__global__ __launch_bounds__(256) void k_lnred(const float* __restrict__ Ppart, u16* __restrict__ out,
    const float* __restrict__ bias, long strideB,
    const float* __restrict__ gamma, const float* __restrict__ beta, long strideLn,
    int MT, int ngroups, int KS, int Mreal, long strideR, long strideG)
{
  const int bid = blockIdx.x, g = bid/Mreal, rr = bid%Mreal, t = threadIdx.x;
  __shared__ float red[8];
  float v[3];
  #pragma unroll
  for (int i=0;i<3;i++) {
    const int e = t + i*256;
    float s = bias[(size_t)g*strideB + e];
    for (int ks=0; ks<KS; ++ks) s += Ppart[((size_t)(ks*ngroups+g)*MT + rr)*768 + e];
    v[i] = s;
  }
  float mean, rstd;
  ln_stats(v[0],v[1],v[2], red, t, mean, rstd);
  #pragma unroll
  for (int i=0;i<3;i++) {
    const int e = t + i*256;
    out[(size_t)rr*strideR + (size_t)g*strideG + e] =
        f2bf(fmaxf((v[i]-mean)*rstd*gamma[(size_t)g*strideLn+e]+beta[(size_t)g*strideLn+e], 0.f));
  }
}

// ---------------- graph: comb (blocks 0-14) + sent init (blocks 15+) --------
__global__ __launch_bounds__(256) void k_comb_si(const float* __restrict__ node_all,
    const float* __restrict__ edge_all, u16* __restrict__ comb,
    const float* __restrict__ se, float* __restrict__ sent)
{
  const int bid = blockIdx.x, t = threadIdx.x;
  if (bid < NLL*NCC) {
    const int ll = bid/NCC, c = bid%NCC;
    const float* node = node_all + (size_t)ll*NCC*EE;
    const float* edge = edge_all + (size_t)ll*3*EE;
    #pragma unroll
    for (int i=0;i<3;i++) {
      const int e = t + i*256;
      float n0=node[e], n1=node[EE+e], n2=node[2*EE+e], n3=node[3*EE+e];
      float nc_=node[(size_t)c*EE+e];
      float e0=edge[e], e1=edge[EE+e], e2=edge[2*EE+e];
      float s0;
      if (c==0) s0=n1+n2; else if (c==1) s0=n0+n2; else if (c==2) s0=n0+n1+n3; else if (c==3) s0=n2; else s0=0.f;
      float ef = (s0*e0 + ((c==3)? n2*e1 : 0.f) + nc_*e2)*(1.0f/3.0f);
      comb[(size_t)bid*2*EE + e]      = f2bf(nc_);
      comb[(size_t)bid*2*EE + EE + e] = f2bf(ef);
    }
  } else {
    const int i = (bid - NLL*NCC)*256 + t;
    if (i < NB*EE) sent[i] = se[i];
  }
}

// ---------------- graph attention tail (+actprep on last layer) --------------
__global__ __launch_bounds__(256) void k_attn2(int l, const float* __restrict__ qpart,
    const float* __restrict__ bq,
    const float* __restrict__ presence, const float* __restrict__ upd, const float* __restrict__ khg,
    float* __restrict__ sent, float* __restrict__ sc_ws, float* __restrict__ out_scores,
    u16* __restrict__ actB, u16* __restrict__ cat)
{
  const int b = blockIdx.x, t = threadIdx.x;
  __shared__ float qh[EE];
  __shared__ float scl[HH][NCC];
  __shared__ float wsc[NCC];
  __shared__ float scr[NCC];
  #pragma unroll
  for (int i=0;i<3;i++) {
    const int e = t + i*256;
    float s = bq[e];
    #pragma unroll
    for (int ks=0; ks<8; ++ks) s += qpart[((size_t)ks*NB + b)*768 + e];
    qh[e] = s;
  }
  __syncthreads();
  if (t < HH*NCC) {
    const int hh=t/NCC, cc=t%NCC;
    const float* kr = khg + (size_t)(l*NCC+cc)*EE + hh*DD;
    float a=0.f;
    #pragma unroll 8
    for (int d=0;d<DD;d++) a += qh[hh*DD+d]*kr[d];
    scl[hh][cc]=a*0.1020620726159658f;
  }
  __syncthreads();
  if (t < HH) {
    float m=scl[t][0];
    #pragma unroll
    for (int c2=1;c2<NCC;c2++) m=fmaxf(m,scl[t][c2]);
    float ex[NCC]; float s=0.f;
    #pragma unroll
    for (int c2=0;c2<NCC;c2++){ ex[c2]=__expf(scl[t][c2]-m); s+=ex[c2]; }
    #pragma unroll
    for (int c2=0;c2<NCC;c2++) scl[t][c2]=ex[c2]/s;
  }
  __syncthreads();
  if (t < NCC) {
    float wv=0.f;
    #pragma unroll
    for (int hh=0;hh<HH;hh++) wv += scl[hh][t];
    wv *= (1.0f/HH);
    wsc[t] = wv*(presence[b*NCC+t]+0.1f);
  }
  __syncthreads();
  if (t==0) {
    float m=wsc[0];
    #pragma unroll
    for (int c2=1;c2<NCC;c2++) m=fmaxf(m,wsc[c2]);
    float ex[NCC]; float s=0.f;
    #pragma unroll
    for (int c2=0;c2<NCC;c2++){ ex[c2]=__expf(wsc[c2]-m); s+=ex[c2]; }
    #pragma unroll
    for (int c2=0;c2<NCC;c2++){
      float v=ex[c2]/s; scr[c2]=v; sc_ws[b*NCC+c2]=v;
      if (out_scores) out_scores[b*NCC+c2]=v;
    }
  }
  __syncthreads();
  #pragma unroll
  for (int i=0;i<3;i++) {
    const int e=t+i*256;
    float a=0.f;
    #pragma unroll
    for (int c2=0;c2<NCC;c2++) a += scr[c2]*upd[(size_t)(l*NCC+c2)*EE+e];
    const float sn = sent[(size_t)b*EE+e] + a*(1.0f/NCC);
    sent[(size_t)b*EE+e] = sn;
    if (out_scores) {            // last layer: absorb actprep
      const u16 snb = f2bf(sn);
      #pragma unroll
      for (int c2=0;c2<NCC;c2++) {
        actB[((size_t)c2*NB + b)*EE + e] = f2bf(upd[(size_t)(2*NCC+c2)*EE + e]*scr[c2]);
        cat[((size_t)(b*NCC+c2))*2*EE + EE + e] = snb;
      }
    }
  }
}

// ---------------- fused attention: per (b, h, 8 q-tiles) --------------------
__global__ __launch_bounds__(256) void attn_k(u16* __restrict__ Q, const u16* __restrict__ Kb,
                                              const u16* __restrict__ Vt)
{
  const int qs = blockIdx.x, h = blockIdx.y, b = blockIdx.z;
  const int t = threadIdx.x, l = t&63, w = t>>6, wr = w>>1, wc = w&1, lm = l&15, lg = l>>4;
  __shared__ u16 Ps[64][136];
  __shared__ float reds[2][64];
  const u16* kb = Kb + ((size_t)b*SEQ)*EE + h*DD;
  const u16* vb = Vt + ((size_t)(b*HH+h))*DD*SEQ;
  u16* qbase = Q + ((size_t)(b*HH+h)*PP + (size_t)qs*512)*DD;
  const float scale = 0.1020620726159658f; // 1/sqrt(96)

  short8 bv[3][4], vv[4][3];
  #pragma unroll
  for (int kc=0;kc<3;kc++)
    #pragma unroll
    for (int ni=0;ni<4;ni++)
      bv[kc][ni] = *(const short8*)(kb + (size_t)(wc*64+ni*16+lm)*EE + kc*32 + lg*8);
  #pragma unroll
  for (int kc=0;kc<4;kc++)
    #pragma unroll
    for (int ni=0;ni<3;ni++)
      vv[kc][ni] = *(const short8*)(vb + (size_t)(wc*48+ni*16+lm)*SEQ + kc*32 + lg*8);

  short8 af[3][2];
  #pragma unroll
  for (int kc=0;kc<3;kc++)
    #pragma unroll
    for (int mi=0;mi<2;mi++)
      af[kc][mi] = *(const short8*)(qbase + (size_t)(wr*32+mi*16+lm)*DD + kc*32 + lg*8);

  for (int it=0; it<8; ++it) {
    u16* qb = qbase + (size_t)it*64*DD;
    f32x4 acc[2][4] = {};
    #pragma unroll
    for (int kc=0;kc<3;kc++)
      #pragma unroll
      for (int mi=0;mi<2;mi++)
        #pragma unroll
        for (int ni=0;ni<4;ni++)
          acc[mi][ni] = __builtin_amdgcn_mfma_f32_16x16x32_bf16(af[kc][mi], bv[kc][ni], acc[mi][ni], 0,0,0);
    if (it < 7) {
      const u16* qn = qb + (size_t)64*DD;
      #pragma unroll
      for (int kc=0;kc<3;kc++)
        #pragma unroll
        for (int mi=0;mi<2;mi++)
          af[kc][mi] = *(const short8*)(qn + (size_t)(wr*32+mi*16+lm)*DD + kc*32 + lg*8);
    }
    float gsum[2][4];
    #pragma unroll
    for (int mi=0;mi<2;mi++)
      #pragma unroll
      for (int r=0;r<4;r++) {
        float s=0.f;
        #pragma unroll
        for (int ni=0;ni<4;ni++) {
          float p = __expf(acc[mi][ni][r]*scale);
          acc[mi][ni][r]=p; s+=p;
        }
        #pragma unroll
        for (int mk=1;mk<16;mk<<=1) s += __shfl_xor(s,mk,64);
        gsum[mi][r]=s;
      }
    if (lm==0) {
      #pragma unroll
      for (int mi=0;mi<2;mi++)
        #pragma unroll
        for (int r=0;r<4;r++) reds[wc][wr*32+mi*16+lg*4+r] = gsum[mi][r];
    }
    __syncthreads();
    #pragma unroll
    for (int mi=0;mi<2;mi++)
      #pragma unroll
      for (int r=0;r<4;r++) {
        const int row = wr*32+mi*16+lg*4+r;
        const float inv = 1.0f/(reds[0][row]+reds[1][row]);
        #pragma unroll
        for (int ni=0;ni<4;ni++)
          Ps[row][wc*64+ni*16+lm] = f2bf(acc[mi][ni][r]*inv);
      }
    __syncthreads();

    f32x4 oacc[2][3] = {};
    #pragma unroll
    for (int kc=0;kc<4;kc++) {
      short8 pa[2];
      #pragma unroll
      for (int mi=0;mi<2;mi++) pa[mi] = *(const short8*)&Ps[wr*32+mi*16+lm][kc*32+lg*8];
      #pragma unroll
      for (int mi=0;mi<2;mi++)
        #pragma unroll
        for (int ni=0;ni<3;ni++)
          oacc[mi][ni] = __builtin_amdgcn_mfma_f32_16x16x32_bf16(pa[mi], vv[kc][ni], oacc[mi][ni], 0,0,0);
    }
    #pragma unroll
    for (int mi=0;mi<2;mi++)
      #pragma unroll
      for (int ni=0;ni<3;ni++)
        #pragma unroll
        for (int r=0;r<4;r++)
          qb[(size_t)(wr*32+mi*16+lg*4+r)*DD + wc*48+ni*16+lm] = f2bf(oacc[mi][ni][r]);
    __syncthreads();   // protect Ps/reds reuse next iteration
  }
}

// ---------------- row LayerNorm in-place (bf16 data, f32 params) -------------
__global__ __launch_bounds__(256) void k_ln(u16* __restrict__ G, const float* __restrict__ gw, const float* __restrict__ gb)
{
  const int row = blockIdx.x, t = threadIdx.x;
  u16* p = G + (size_t)row*EE;
  __shared__ float red[8];
  float v[3];
  #pragma unroll
  for (int i=0;i<3;i++) v[i]=bf2f(p[t+i*256]);
  float mean, rstd;
  ln_stats(v[0],v[1],v[2], red, t, mean, rstd);
  #pragma unroll
  for (int i=0;i<3;i++) {
    const int e=t+i*256;
    p[e]=f2bf((v[i]-mean)*rstd*gw[e]+gb[e]);
  }
}

// ---------------- host launch ------------------------------------------------
extern "C" void kernel_launch(void* const* d_in, const int* in_sizes, int n_in,
                              void* d_out, int out_size, void* d_ws, size_t ws_size,
                              hipStream_t stream)
{
  const float* visual   = (const float*)d_in[0];
  const float* text     = (const float*)d_in[1];
  const float* sentemb  = (const float*)d_in[2];
  const float* presence = (const float*)d_in[3];
  const float* gnode = (const float*)d_in[4];
  const float* gedge = (const float*)d_in[5];
  const float* gWqkv = (const float*)d_in[6];
  const float* gbqkv = (const float*)d_in[7];
  const float* gW1 = (const float*)d_in[10];
  const float* gb1 = (const float*)d_in[11];
  const float* glng = (const float*)d_in[12];
  const float* glnb = (const float*)d_in[13];
  const float* gW2 = (const float*)d_in[14];
  const float* gb2 = (const float*)d_in[15];
  const float* vWqkv = (const float*)d_in[16];
  const float* vbqkv = (const float*)d_in[17];
  const float* vWo = (const float*)d_in[18];
  const float* vbo = (const float*)d_in[19];
  const float* cW1 = (const float*)d_in[20];
  const float* cb1 = (const float*)d_in[21];
  const float* clng = (const float*)d_in[22];
  const float* clnb = (const float*)d_in[23];
  const float* cW2 = (const float*)d_in[24];
  const float* cb2 = (const float*)d_in[25];
  const float* gfW1 = (const float*)d_in[26];
  const float* gfb1 = (const float*)d_in[27];
  const float* gflng = (const float*)d_in[28];
  const float* gflnb = (const float*)d_in[29];
  const float* gfW2 = (const float*)d_in[30];
  const float* gfb2 = (const float*)d_in[31];
  const float* outW = (const float*)d_in[32];
  const float* outb = (const float*)d_in[33];
  const float* normg = (const float*)d_in[34];
  const float* normb = (const float*)d_in[35];

  // ---- d_ws layout ----
  char* ws = (char*)d_ws;
  u16* wsG   = (u16*)(ws);                    // 32768x768 bf16 (pre-LN / grounded)
  u16* wsK   = (u16*)(ws + 50331648);         // 4096x768 bf16 (attn K); dead after attn
  u16* wsVt  = (u16*)(ws + 56623104);         // V^T bf16
  u16* visB  = (u16*)(ws + 62914560);         // visual bf16 32768x768
  u16* outWB = wsK;                           // outW bf16 overlays dead wsK post-attn

  // ---- d_out scratch (dead before out-proj writes) ----
  char* dob = (char*)d_out;
  u16* wsQ    = (u16*)(dob);                  // head-major Q' [b][h][1024][96] bf16
  u16* textB  = (u16*)(dob + 50331648);       // 4096x768 bf16
  u16* WqkvB  = (u16*)(dob + 56623104);       // 2304x768 bf16
  u16* WoB    = (u16*)(dob + 60162048);       // 768x768 bf16
  char* P = dob + 61341696;                   // graph/class scratch
  float* wsSent   = (float*)(P);              //  32x768 f32
  float* wsUpd    = (float*)(P +   98304);    //  15x768 f32
  float* wsKhg    = (float*)(P +  144384);    //  15x768 f32
  float* wsScores = (float*)(P +  190464);    //  160 f32
  u16*   wsComb   = (u16*)  (P +  191104);    //  15x1536 bf16
  u16*   wsHb     = (u16*)  (P +  237184);    //  15x768 bf16
  u16*   wsUpdB   = (u16*)  (P +  260224);    //  15x768 bf16
  u16*   wsActB   = (u16*)  (P +  283264);    //  5x32x768 bf16
  u16*   wsH1b    = (u16*)  (P +  529024);    //  160x768 bf16
  u16*   wsCat    = (u16*)  (P +  774784);    //  160x1536 bf16
  u16*   wsG1b    = (u16*)  (P + 1266304);    //  160x768 bf16
  float* Ppart    = (float*)(P + 1512064);    //  ~2 MB f32 partials

  float* outGO = (float*)d_out;
  float* outCG = outGO + 25165824;
  float* outSC = outGO + 25288704;

  // ---- conversions (one fused launch) ----
  k_cvt4<<<dim3(2048), dim3(256), 0, stream>>>(visual, visB, 3145728,
                                               text, textB, 393216,
                                               vWqkv, WqkvB, 221184,
                                               vWo, WoB, 73728);

  // ---- graph node-update chain (split-K task GEMMs) ----
  k_comb_si<<<dim3(NLL*NCC + 96), dim3(256), 0, stream>>>(gnode, gedge, wsComb, sentemb, wsSent);
  gemm_tk<16,0><<<dim3(144), dim3(256), 0, stream>>>(wsComb, gW1, Ppart,
      3, 8, 2*EE, 2*EE, (long)NCC*2*EE, (long)EE*2*EE);
  k_lnred<<<dim3(15), dim3(256), 0, stream>>>(Ppart, wsHb, gb1, EE, glng, glnb, EE,
      16, 3, 8, 5, 768, 3840);
  gemm_tk<16,0><<<dim3(72), dim3(256), 0, stream>>>(wsHb, gW2, Ppart,
      3, 4, EE, EE, (long)NCC*EE, (long)EE*EE);
  k_red<<<dim3(15), dim3(256), 0, stream>>>(Ppart, wsUpd, wsUpdB, gb2, EE,
      16, 3, 4, 5, 768, 3840);
  gemm_tk<16,0><<<dim3(72), dim3(256), 0, stream>>>(wsUpdB, gWqkv + (size_t)EE*EE, Ppart,
      3, 4, EE, EE, (long)NCC*EE, (long)3*EE*EE);
  k_red<<<dim3(15), dim3(256), 0, stream>>>(Ppart, wsKhg, nullptr, gbqkv + EE, (long)3*EE,
      16, 3, 4, 5, 768, 3840);

  // ---- sentence loop (l==2 absorbs actprep) ----
  for (int l=0;l<NLL;l++) {
    gemm_tk<32,1><<<dim3(48), dim3(256), 0, stream>>>(wsSent, gWqkv + (size_t)l*3*EE*EE, Ppart,
        1, 8, EE, EE, 0, 0);
    k_attn2<<<dim3(NB), dim3(256), 0, stream>>>(l, Ppart, gbqkv + (size_t)l*3*EE,
        presence, wsUpd, wsKhg, wsSent, wsScores,
        (l==NLL-1)?outSC:(float*)nullptr, wsActB, wsCat);
  }

  // ---- class guidance chain ----
  gemm_tk<32,0><<<dim3(120), dim3(256), 0, stream>>>(wsActB, cW1, Ppart,
      5, 4, EE, EE, (long)NB*EE, (long)EE*EE);
  k_lnred<<<dim3(160), dim3(256), 0, stream>>>(Ppart, wsH1b, cb1, EE, clng, clnb, EE,
      32, 5, 4, 32, 768, 24576);
  gemm_tk<32,0><<<dim3(120), dim3(256), 0, stream>>>(wsH1b, cW2, Ppart,
      5, 4, EE, EE, (long)NB*EE, (long)EE*EE);
  k_red<<<dim3(160), dim3(256), 0, stream>>>(Ppart, nullptr, wsCat, cb2, EE,
      32, 5, 4, 32, 7680, 1536);
  gemm_tk<32,0><<<dim3(120), dim3(256), 0, stream>>>(wsCat, gfW1, Ppart,
      5, 4, 2*EE, 2*EE, (long)NB*2*EE, 0);
  k_lnred<<<dim3(160), dim3(256), 0, stream>>>(Ppart, wsG1b, gfb1, 0, gflng, gflnb, 0,
      32, 5, 4, 32, 768, 24576);
  gemm_tk<32,0><<<dim3(120), dim3(256), 0, stream>>>(wsG1b, gfW2, Ppart,
      5, 4, EE, EE, (long)NB*EE, 0);
  k_red<<<dim3(160), dim3(256), 0, stream>>>(Ppart, outCG, nullptr, gfb2, 0,
      32, 5, 4, 32, 768, 24576);

  // ---- visual-text fusion (XCD-swizzled 1-D grids; 256x128 tiles) ----
  gemm_bt<4,0><<<dim3(768), dim3(256), 0, stream>>>(visB, WqkvB, vbqkv, nullptr,
                                                    wsQ, nullptr, nullptr, NB*PP, EE, EE, 6);
  gemm_bt<2,0><<<dim3(192), dim3(256), 0, stream>>>(textB, WqkvB + (size_t)EE*EE, vbqkv+EE, nullptr,
                                                    wsK, nullptr, wsVt, NB*SEQ, 2*EE, EE, 12);
  attn_k<<<dim3(2, HH, NB), dim3(256), 0, stream>>>(wsQ, wsK, wsVt);
  k_cvt<<<dim3(512), dim3(256), 0, stream>>>(outW, outWB, 73728);   // into dead wsK (d_ws)
  gemm_bt<1,1><<<dim3(768), dim3(256), 0, stream>>>(wsQ, WoB, vbo, visB,
                                                    wsG, nullptr, nullptr, NB*PP, EE, EE, 6);
  k_ln<<<dim3(NB*PP), dim3(256), 0, stream>>>(wsG, normg, normb);
  gemm_bt<3,0><<<dim3(768), dim3(256), 0, stream>>>(wsG, outWB, outb, nullptr,
                                                    nullptr, outGO, nullptr, NB*PP, EE, EE, 6);
}

// Round 20
// 432.304 us; speedup vs baseline: 1.1037x; 1.1037x over previous
//
#include <hip/hip_runtime.h>
#include <stdint.h>

typedef unsigned short u16;
typedef __attribute__((ext_vector_type(8))) short short8;
typedef __attribute__((ext_vector_type(4))) float f32x4;

#define NB 32
#define PP 1024
#define SEQ 128
#define EE 768
#define HH 8
#define DD 96
#define NCC 5
#define NLL 3

__device__ __forceinline__ float bf2f(u16 x){ unsigned u=((unsigned)x)<<16; float f; __builtin_memcpy(&f,&u,4); return f; }
__device__ __forceinline__ u16 f2bf(float f){ unsigned u; __builtin_memcpy(&u,&f,4); u=(u+0x7FFFu+((u>>16)&1u))>>16; return (u16)u; }

__device__ __forceinline__ short8 cvt8(const float* p) {
  f32x4 a = *(const f32x4*)p;
  f32x4 b = *(const f32x4*)(p+4);
  short8 r;
  r[0]=(short)f2bf(a[0]); r[1]=(short)f2bf(a[1]); r[2]=(short)f2bf(a[2]); r[3]=(short)f2bf(a[3]);
  r[4]=(short)f2bf(b[0]); r[5]=(short)f2bf(b[1]); r[6]=(short)f2bf(b[2]); r[7]=(short)f2bf(b[3]);
  return r;
}

__device__ __forceinline__ void gl16(const u16* g, u16* l) {
  __builtin_amdgcn_global_load_lds((const __attribute__((address_space(1))) void*)g,
                                   (__attribute__((address_space(3))) void*)l, 16, 0, 0);
}

// head-major A address: element (row fixed in aBase, k) of Q'[b][h][1024][96]
__device__ __forceinline__ const u16* ah_addr(const u16* aBase, int k0) {
  const int h = k0/96;
  return aBase + (size_t)h*98304 + (k0 - h*96);
}

// ---------------- fused f32 -> bf16 bulk convert (4 segments, 1 launch) -----
__global__ __launch_bounds__(256) void k_cvt4(
    const float* __restrict__ s0, u16* __restrict__ d0, int c0,
    const float* __restrict__ s1, u16* __restrict__ d1, int c1,
    const float* __restrict__ s2, u16* __restrict__ d2, int c2,
    const float* __restrict__ s3, u16* __restrict__ d3, int c3)
{
  int i = blockIdx.x*256 + threadIdx.x;
  const int stride = gridDim.x*256;
  const int tot = c0+c1+c2+c3;
  for (; i < tot; i += stride) {
    int j = i; const float* s; u16* d;
    if (j < c0) { s=s0; d=d0; }
    else { j-=c0; if (j<c1){s=s1;d=d1;}
      else { j-=c1; if (j<c2){s=s2;d=d2;} else { j-=c2; s=s3; d=d3; } } }
    *(short8*)(d + (size_t)j*8) = cvt8(s + (size_t)j*8);
  }
}

__global__ __launch_bounds__(256) void k_cvt(const float* __restrict__ s, u16* __restrict__ d, int n8) {
  int i = blockIdx.x*256 + threadIdx.x;
  const int stride = gridDim.x*256;
  for (; i < n8; i += stride) *(short8*)(d + (size_t)i*8) = cvt8(s + (size_t)i*8);
}

// ---------------- block LN stats helper (256 threads, 3 vals/thread) --------
__device__ __forceinline__ void ln_stats(float v0, float v1, float v2, float* red, int t,
                                         float& mean, float& rstd) {
  float ps = v0+v1+v2;
  float ps2 = v0*v0+v1*v1+v2*v2;
  #pragma unroll
  for (int o=32;o;o>>=1){ ps += __shfl_down(ps,o,64); ps2 += __shfl_down(ps2,o,64); }
  if ((t&63)==0){ red[t>>6]=ps; red[4+(t>>6)]=ps2; }
  __syncthreads();
  mean = (red[0]+red[1]+red[2]+red[3])*(1.0f/EE);
  float var = (red[4]+red[5]+red[6]+red[7])*(1.0f/EE) - mean*mean;
  rstd = rsqrtf(var + 1e-5f);
  __syncthreads();
}

// ---------------- big GEMM: 2-deep counted-vmcnt pipeline (32KB LDS) --------
template<int EPI, int AH>
__global__ __launch_bounds__(256) void gemm_bt(const u16* __restrict__ A, const u16* __restrict__ Bw,
        const float* __restrict__ bias, const u16* __restrict__ Res,
        u16* __restrict__ C, float* __restrict__ Cf, u16* __restrict__ C2,
        int M, int N, int K, int NTB)
{
  __shared__ u16 As[2][4096];
  __shared__ u16 Bs[2][4096];
  const int nwg = gridDim.x;
  const int bid = blockIdx.x;
  const int task = (bid & 7)*(nwg >> 3) + (bid >> 3);
  const int m0 = (task / NTB)*128, n0 = (task % NTB)*128;
  const int t = threadIdx.x;
  const int lane = t&63, w = t>>6, wr = w>>1, wc = w&1, lm = lane&15, lg = lane>>4;
  const int o   = w*1024 + lane*16;
  const int srow = o>>6;
  const int sg   = ((o>>4)&3) ^ ((srow>>1)&3);
  const int row0 = m0 + srow;
  const u16* ag    = A + (size_t)row0*K + sg*8;                       // AH=0
  const u16* aBase = A + (size_t)((row0>>10)*8)*98304                  // AH=1
                       + (size_t)(row0&1023)*96 + sg*8;
  const u16* bg = Bw + (size_t)(n0+srow)*K + sg*8;
  const size_t rstepA = (size_t)64*K;     // AH=0 row+64
  const size_t rstepH = 6144;             // AH=1 row+64 (64*96, same b,h)
  const int s  = (lm>>1)&3;
  const int ra = (wr*64+lm)*32 + (lg^s)*8;
  const int rb = (wc*64+lm)*32 + (lg^s)*8;
  const int NT = K>>5;

  f32x4 acc[4][4] = {};
  #pragma unroll
  for (int p=0;p<2;p++) {
    const int k0 = p<<5;
    if constexpr (AH) {
      const u16* pa = ah_addr(aBase, k0);
      gl16(pa,          &As[p][w*512]);
      gl16(pa + rstepH, &As[p][2048 + w*512]);
    } else {
      gl16(ag + k0,          &As[p][w*512]);
      gl16(ag + k0 + rstepA, &As[p][2048 + w*512]);
    }
    gl16(bg + k0,          &Bs[p][w*512]);
    gl16(bg + k0 + rstepA, &Bs[p][2048 + w*512]);
  }
  int cur = 0;
  for (int kt=0; kt<NT; ++kt) {
    if (kt+1 < NT) { asm volatile("s_waitcnt vmcnt(4)" ::: "memory"); }
    else           { asm volatile("s_waitcnt vmcnt(0)" ::: "memory"); }
    __builtin_amdgcn_sched_barrier(0);
    __builtin_amdgcn_s_barrier();          // tile kt visible to all waves
    short8 af[4], bf[4];
    #pragma unroll
    for (int mi=0;mi<4;mi++) af[mi] = *(const short8*)&As[cur][ra + mi*512];
    #pragma unroll
    for (int ni=0;ni<4;ni++) bf[ni] = *(const short8*)&Bs[cur][rb + ni*512];
    asm volatile("s_waitcnt lgkmcnt(0)" ::: "memory");  // frags in regs
    __builtin_amdgcn_sched_barrier(0);
    __builtin_amdgcn_s_barrier();          // all waves done reading buf cur
    if (kt+2 < NT) {                       // refill freed buffer (tile kt+2)
      const int k0 = (kt+2)<<5;
      if constexpr (AH) {
        const u16* pa = ah_addr(aBase, k0);
        gl16(pa,          &As[cur][w*512]);
        gl16(pa + rstepH, &As[cur][2048 + w*512]);
      } else {
        gl16(ag + k0,          &As[cur][w*512]);
        gl16(ag + k0 + rstepA, &As[cur][2048 + w*512]);
      }
      gl16(bg + k0,          &Bs[cur][w*512]);
      gl16(bg + k0 + rstepA, &Bs[cur][2048 + w*512]);
    }
    #pragma unroll
    for (int mi=0;mi<4;mi++)
      #pragma unroll
      for (int ni=0;ni<4;ni++)
        acc[mi][ni] = __builtin_amdgcn_mfma_f32_16x16x32_bf16(af[mi], bf[ni], acc[mi][ni], 0,0,0);
    cur ^= 1;
  }
  #pragma unroll
  for (int mi=0;mi<4;mi++) {
    #pragma unroll
    for (int ni=0;ni<4;ni++) {
      const int col = n0 + wc*64 + ni*16 + lm;
      const float bv = bias[col];
      const int hq = (n0 + wc*64 + ni*16)/96;     // head idx (16-col groups never cross)
      const int dq = col - hq*96;
      #pragma unroll
      for (int r=0;r<4;r++) {
        const int row = m0 + wr*64 + mi*16 + lg*4 + r;
        float v = acc[mi][ni][r] + bv;
        if constexpr (EPI==1) v += bf2f(Res[(size_t)row*N + col]);
        if constexpr (EPI==3) {
          Cf[(size_t)row*N + col] = v;
        } else if constexpr (EPI==2) {
          if (col < EE) C[(size_t)row*EE + col] = f2bf(v);
          else C2[((size_t)(row>>7)*EE + (col-EE))*SEQ + (row&127)] = f2bf(v);
        } else if constexpr (EPI==4) {
          C[((size_t)((row>>10)*8 + hq)*1024 + (row&1023))*96 + dq] = f2bf(v);
        } else {
          C[(size_t)row*N + col] = f2bf(v);
        }
      }
    }
  }
}

// ---------------- task GEMM: split-K partials, no barriers, no LDS ----------
template<int MT, int AF>
__global__ __launch_bounds__(256) void gemm_tk(const void* __restrict__ Av, const float* __restrict__ W,
    float* __restrict__ Ppart, int ngroups, int KS, int K, int lda, long strideA, long strideW)
{
  const int task = blockIdx.x;
  const int nt = task % 6;
  const int g  = (task/6) % ngroups;
  const int ks = task/(6*ngroups);
  const int t = threadIdx.x, l = t&63, w = t>>6, lm = l&15, lg = l>>4;
  const int slice = K/KS, kbase = ks*slice;
  const int n0 = nt*128 + w*32;
  W += (size_t)g*strideW;
  f32x4 acc[MT/16][2] = {};
  for (int ki=0; ki<slice; ki+=32) {
    const int k0 = kbase + ki;
    short8 af[MT/16];
    #pragma unroll
    for (int m=0;m<MT/16;m++) {
      if constexpr (AF) af[m] = cvt8((const float*)Av + (size_t)g*strideA + (size_t)(m*16+lm)*lda + k0 + lg*8);
      else af[m] = *(const short8*)((const u16*)Av + (size_t)g*strideA + (size_t)(m*16+lm)*lda + k0 + lg*8);
    }
    #pragma unroll
    for (int ni=0;ni<2;ni++) {
      const short8 bf = cvt8(W + (size_t)(n0+ni*16+lm)*K + k0 + lg*8);
      #pragma unroll
      for (int m=0;m<MT/16;m++)
        acc[m][ni] = __builtin_amdgcn_mfma_f32_16x16x32_bf16(af[m], bf, acc[m][ni], 0,0,0);
    }
  }
  float* pb = Ppart + (size_t)(ks*ngroups+g)*MT*768;
  #pragma unroll
  for (int m=0;m<MT/16;m++)
    #pragma unroll
    for (int ni=0;ni<2;ni++)
      #pragma unroll
      for (int r=0;r<4;r++)
        pb[(size_t)(m*16+lg*4+r)*768 + n0+ni*16+lm] = acc[m][ni][r];
}

// ---------------- reduce partials + bias (+LN+relu variant) ------------------
__global__ __launch_bounds__(256) void k_red(const float* __restrict__ Ppart,
    float* __restrict__ outF, u16* __restrict__ outB,
    const float* __restrict__ bias, long strideB,
    int MT, int ngroups, int KS, int Mreal, long strideR, long strideG)
{
  const int bid = blockIdx.x, g = bid/Mreal, rr = bid%Mreal, t = threadIdx.x;
  #pragma unroll
  for (int i=0;i<3;i++) {
    const int e = t + i*256;
    float s = bias[(size_t)g*strideB + e];
    for (int ks=0; ks<KS; ++ks) s += Ppart[((size_t)(ks*ngroups+g)*MT + rr)*768 + e];
    const size_t off = (size_t)rr*strideR + (size_t)g*strideG + e;
    if (outF) outF[off] = s;
    if (outB) outB[off] = f2bf(s);
  }
}

__global__ __launch_bounds__(256) void k_lnred(const float* __restrict__ Ppart, u16* __restrict__ out,
    const float* __restrict__ bias, long strideB,
    const float* __restrict__ gamma, const float* __restrict__ beta, long strideLn,
    int MT, int ngroups, int KS, int Mreal, long strideR, long strideG)
{
  const int bid = blockIdx.x, g = bid/Mreal, rr = bid%Mreal, t = threadIdx.x;
  __shared__ float red[8];
  float v[3];
  #pragma unroll
  for (int i=0;i<3;i++) {
    const int e = t + i*256;
    float s = bias[(size_t)g*strideB + e];
    for (int ks=0; ks<KS; ++ks) s += Ppart[((size_t)(ks*ngroups+g)*MT + rr)*768 + e];
    v[i] = s;
  }
  float mean, rstd;
  ln_stats(v[0],v[1],v[2], red, t, mean, rstd);
  #pragma unroll
  for (int i=0;i<3;i++) {
    const int e = t + i*256;
    out[(size_t)rr*strideR + (size_t)g*strideG + e] =
        f2bf(fmaxf((v[i]-mean)*rstd*gamma[(size_t)g*strideLn+e]+beta[(size_t)g*strideLn+e], 0.f));
  }
}

// ---------------- graph: comb (blocks 0-14) + sent init (blocks 15+) --------
__global__ __launch_bounds__(256) void k_comb_si(const float* __restrict__ node_all,
    const float* __restrict__ edge_all, u16* __restrict__ comb,
    const float* __restrict__ se, float* __restrict__ sent)
{
  const int bid = blockIdx.x, t = threadIdx.x;
  if (bid < NLL*NCC) {
    const int ll = bid/NCC, c = bid%NCC;
    const float* node = node_all + (size_t)ll*NCC*EE;
    const float* edge = edge_all + (size_t)ll*3*EE;
    #pragma unroll
    for (int i=0;i<3;i++) {
      const int e = t + i*256;
      float n0=node[e], n1=node[EE+e], n2=node[2*EE+e], n3=node[3*EE+e];
      float nc_=node[(size_t)c*EE+e];
      float e0=edge[e], e1=edge[EE+e], e2=edge[2*EE+e];
      float s0;
      if (c==0) s0=n1+n2; else if (c==1) s0=n0+n2; else if (c==2) s0=n0+n1+n3; else if (c==3) s0=n2; else s0=0.f;
      float ef = (s0*e0 + ((c==3)? n2*e1 : 0.f) + nc_*e2)*(1.0f/3.0f);
      comb[(size_t)bid*2*EE + e]      = f2bf(nc_);
      comb[(size_t)bid*2*EE + EE + e] = f2bf(ef);
    }
  } else {
    const int i = (bid - NLL*NCC)*256 + t;
    if (i < NB*EE) sent[i] = se[i];
  }
}

// ---------------- graph attention tail (+actprep on last layer) --------------
__global__ __launch_bounds__(256) void k_attn2(int l, const float* __restrict__ qpart,
    const float* __restrict__ bq,
    const float* __restrict__ presence, const float* __restrict__ upd, const float* __restrict__ khg,
    float* __restrict__ sent, float* __restrict__ sc_ws, float* __restrict__ out_scores,
    u16* __restrict__ actB, u16* __restrict__ cat)
{
  const int b = blockIdx.x, t = threadIdx.x;
  __shared__ float qh[EE];
  __shared__ float scl[HH][NCC];
  __shared__ float wsc[NCC];
  __shared__ float scr[NCC];
  #pragma unroll
  for (int i=0;i<3;i++) {
    const int e = t + i*256;
    float s = bq[e];
    #pragma unroll
    for (int ks=0; ks<8; ++ks) s += qpart[((size_t)ks*NB + b)*768 + e];
    qh[e] = s;
  }
  __syncthreads();
  if (t < HH*NCC) {
    const int hh=t/NCC, cc=t%NCC;
    const float* kr = khg + (size_t)(l*NCC+cc)*EE + hh*DD;
    float a=0.f;
    #pragma unroll 8
    for (int d=0;d<DD;d++) a += qh[hh*DD+d]*kr[d];
    scl[hh][cc]=a*0.1020620726159658f;
  }
  __syncthreads();
  if (t < HH) {
    float m=scl[t][0];
    #pragma unroll
    for (int c2=1;c2<NCC;c2++) m=fmaxf(m,scl[t][c2]);
    float ex[NCC]; float s=0.f;
    #pragma unroll
    for (int c2=0;c2<NCC;c2++){ ex[c2]=__expf(scl[t][c2]-m); s+=ex[c2]; }
    #pragma unroll
    for (int c2=0;c2<NCC;c2++) scl[t][c2]=ex[c2]/s;
  }
  __syncthreads();
  if (t < NCC) {
    float wv=0.f;
    #pragma unroll
    for (int hh=0;hh<HH;hh++) wv += scl[hh][t];
    wv *= (1.0f/HH);
    wsc[t] = wv*(presence[b*NCC+t]+0.1f);
  }
  __syncthreads();
  if (t==0) {
    float m=wsc[0];
    #pragma unroll
    for (int c2=1;c2<NCC;c2++) m=fmaxf(m,wsc[c2]);
    float ex[NCC]; float s=0.f;
    #pragma unroll
    for (int c2=0;c2<NCC;c2++){ ex[c2]=__expf(wsc[c2]-m); s+=ex[c2]; }
    #pragma unroll
    for (int c2=0;c2<NCC;c2++){
      float v=ex[c2]/s; scr[c2]=v; sc_ws[b*NCC+c2]=v;
      if (out_scores) out_scores[b*NCC+c2]=v;
    }
  }
  __syncthreads();
  #pragma unroll
  for (int i=0;i<3;i++) {
    const int e=t+i*256;
    float a=0.f;
    #pragma unroll
    for (int c2=0;c2<NCC;c2++) a += scr[c2]*upd[(size_t)(l*NCC+c2)*EE+e];
    const float sn = sent[(size_t)b*EE+e] + a*(1.0f/NCC);
    sent[(size_t)b*EE+e] = sn;
    if (out_scores) {            // last layer: absorb actprep
      const u16 snb = f2bf(sn);
      #pragma unroll
      for (int c2=0;c2<NCC;c2++) {
        actB[((size_t)c2*NB + b)*EE + e] = f2bf(upd[(size_t)(2*NCC+c2)*EE + e]*scr[c2]);
        cat[((size_t)(b*NCC+c2))*2*EE + EE + e] = snb;
      }
    }
  }
}

// ---------------- fused attention: per (b, h, 8 q-tiles) --------------------
__global__ __launch_bounds__(256) void attn_k(u16* __restrict__ Q, const u16* __restrict__ Kb,
                                              const u16* __restrict__ Vt)
{
  const int qs = blockIdx.x, h = blockIdx.y, b = blockIdx.z;
  const int t = threadIdx.x, l = t&63, w = t>>6, wr = w>>1, wc = w&1, lm = l&15, lg = l>>4;
  __shared__ u16 Ps[64][136];
  __shared__ float reds[2][64];
  const u16* kb = Kb + ((size_t)b*SEQ)*EE + h*DD;
  const u16* vb = Vt + ((size_t)(b*HH+h))*DD*SEQ;
  u16* qbase = Q + ((size_t)(b*HH+h)*PP + (size_t)qs*512)*DD;
  const float scale = 0.1020620726159658f; // 1/sqrt(96)

  short8 bv[3][4], vv[4][3];
  #pragma unroll
  for (int kc=0;kc<3;kc++)
    #pragma unroll
    for (int ni=0;ni<4;ni++)
      bv[kc][ni] = *(const short8*)(kb + (size_t)(wc*64+ni*16+lm)*EE + kc*32 + lg*8);
  #pragma unroll
  for (int kc=0;kc<4;kc++)
    #pragma unroll
    for (int ni=0;ni<3;ni++)
      vv[kc][ni] = *(const short8*)(vb + (size_t)(wc*48+ni*16+lm)*SEQ + kc*32 + lg*8);

  short8 af[3][2];
  #pragma unroll
  for (int kc=0;kc<3;kc++)
    #pragma unroll
    for (int mi=0;mi<2;mi++)
      af[kc][mi] = *(const short8*)(qbase + (size_t)(wr*32+mi*16+lm)*DD + kc*32 + lg*8);

  for (int it=0; it<8; ++it) {
    u16* qb = qbase + (size_t)it*64*DD;
    f32x4 acc[2][4] = {};
    #pragma unroll
    for (int kc=0;kc<3;kc++)
      #pragma unroll
      for (int mi=0;mi<2;mi++)
        #pragma unroll
        for (int ni=0;ni<4;ni++)
          acc[mi][ni] = __builtin_amdgcn_mfma_f32_16x16x32_bf16(af[kc][mi], bv[kc][ni], acc[mi][ni], 0,0,0);
    if (it < 7) {
      const u16* qn = qb + (size_t)64*DD;
      #pragma unroll
      for (int kc=0;kc<3;kc++)
        #pragma unroll
        for (int mi=0;mi<2;mi++)
          af[kc][mi] = *(const short8*)(qn + (size_t)(wr*32+mi*16+lm)*DD + kc*32 + lg*8);
    }
    float gsum[2][4];
    #pragma unroll
    for (int mi=0;mi<2;mi++)
      #pragma unroll
      for (int r=0;r<4;r++) {
        float s=0.f;
        #pragma unroll
        for (int ni=0;ni<4;ni++) {
          float p = __expf(acc[mi][ni][r]*scale);
          acc[mi][ni][r]=p; s+=p;
        }
        #pragma unroll
        for (int mk=1;mk<16;mk<<=1) s += __shfl_xor(s,mk,64);
        gsum[mi][r]=s;
      }
    if (lm==0) {
      #pragma unroll
      for (int mi=0;mi<2;mi++)
        #pragma unroll
        for (int r=0;r<4;r++) reds[wc][wr*32+mi*16+lg*4+r] = gsum[mi][r];
    }
    __syncthreads();
    #pragma unroll
    for (int mi=0;mi<2;mi++)
      #pragma unroll
      for (int r=0;r<4;r++) {
        const int row = wr*32+mi*16+lg*4+r;
        const float inv = 1.0f/(reds[0][row]+reds[1][row]);
        #pragma unroll
        for (int ni=0;ni<4;ni++)
          Ps[row][wc*64+ni*16+lm] = f2bf(acc[mi][ni][r]*inv);
      }
    __syncthreads();

    f32x4 oacc[2][3] = {};
    #pragma unroll
    for (int kc=0;kc<4;kc++) {
      short8 pa[2];
      #pragma unroll
      for (int mi=0;mi<2;mi++) pa[mi] = *(const short8*)&Ps[wr*32+mi*16+lm][kc*32+lg*8];
      #pragma unroll
      for (int mi=0;mi<2;mi++)
        #pragma unroll
        for (int ni=0;ni<3;ni++)
          oacc[mi][ni] = __builtin_amdgcn_mfma_f32_16x16x32_bf16(pa[mi], vv[kc][ni], oacc[mi][ni], 0,0,0);
    }
    #pragma unroll
    for (int mi=0;mi<2;mi++)
      #pragma unroll
      for (int ni=0;ni<3;ni++)
        #pragma unroll
        for (int r=0;r<4;r++)
          qb[(size_t)(wr*32+mi*16+lg*4+r)*DD + wc*48+ni*16+lm] = f2bf(oacc[mi][ni][r]);
    __syncthreads();   // protect Ps/reds reuse next iteration
  }
}

// ---------------- row LayerNorm in-place (bf16 data, f32 params) -------------
__global__ __launch_bounds__(256) void k_ln(u16* __restrict__ G, const float* __restrict__ gw, const float* __restrict__ gb)
{
  const int row = blockIdx.x, t = threadIdx.x;
  u16* p = G + (size_t)row*EE;
  __shared__ float red[8];
  float v[3];
  #pragma unroll
  for (int i=0;i<3;i++) v[i]=bf2f(p[t+i*256]);
  float mean, rstd;
  ln_stats(v[0],v[1],v[2], red, t, mean, rstd);
  #pragma unroll
  for (int i=0;i<3;i++) {
    const int e=t+i*256;
    p[e]=f2bf((v[i]-mean)*rstd*gw[e]+gb[e]);
  }
}

// ---------------- host launch ------------------------------------------------
extern "C" void kernel_launch(void* const* d_in, const int* in_sizes, int n_in,
                              void* d_out, int out_size, void* d_ws, size_t ws_size,
                              hipStream_t stream)
{
  const float* visual   = (const float*)d_in[0];
  const float* text     = (const float*)d_in[1];
  const float* sentemb  = (const float*)d_in[2];
  const float* presence = (const float*)d_in[3];
  const float* gnode = (const float*)d_in[4];
  const float* gedge = (const float*)d_in[5];
  const float* gWqkv = (const float*)d_in[6];
  const float* gbqkv = (const float*)d_in[7];
  const float* gW1 = (const float*)d_in[10];
  const float* gb1 = (const float*)d_in[11];
  const float* glng = (const float*)d_in[12];
  const float* glnb = (const float*)d_in[13];
  const float* gW2 = (const float*)d_in[14];
  const float* gb2 = (const float*)d_in[15];
  const float* vWqkv = (const float*)d_in[16];
  const float* vbqkv = (const float*)d_in[17];
  const float* vWo = (const float*)d_in[18];
  const float* vbo = (const float*)d_in[19];
  const float* cW1 = (const float*)d_in[20];
  const float* cb1 = (const float*)d_in[21];
  const float* clng = (const float*)d_in[22];
  const float* clnb = (const float*)d_in[23];
  const float* cW2 = (const float*)d_in[24];
  const float* cb2 = (const float*)d_in[25];
  const float* gfW1 = (const float*)d_in[26];
  const float* gfb1 = (const float*)d_in[27];
  const float* gflng = (const float*)d_in[28];
  const float* gflnb = (const float*)d_in[29];
  const float* gfW2 = (const float*)d_in[30];
  const float* gfb2 = (const float*)d_in[31];
  const float* outW = (const float*)d_in[32];
  const float* outb = (const float*)d_in[33];
  const float* normg = (const float*)d_in[34];
  const float* normb = (const float*)d_in[35];

  // ---- d_ws layout ----
  char* ws = (char*)d_ws;
  u16* wsG   = (u16*)(ws);                    // 32768x768 bf16 (pre-LN / grounded)
  u16* wsK   = (u16*)(ws + 50331648);         // 4096x768 bf16 (attn K); dead after attn
  u16* wsVt  = (u16*)(ws + 56623104);         // V^T bf16
  u16* visB  = (u16*)(ws + 62914560);         // visual bf16 32768x768
  u16* outWB = wsK;                           // outW bf16 overlays dead wsK post-attn

  // ---- d_out scratch (dead before out-proj writes) ----
  char* dob = (char*)d_out;
  u16* wsQ    = (u16*)(dob);                  // head-major Q' [b][h][1024][96] bf16
  u16* textB  = (u16*)(dob + 50331648);       // 4096x768 bf16
  u16* WqkvB  = (u16*)(dob + 56623104);       // 2304x768 bf16
  u16* WoB    = (u16*)(dob + 60162048);       // 768x768 bf16
  char* P = dob + 61341696;                   // graph/class scratch
  float* wsSent   = (float*)(P);              //  32x768 f32
  float* wsUpd    = (float*)(P +   98304);    //  15x768 f32
  float* wsKhg    = (float*)(P +  144384);    //  15x768 f32
  float* wsScores = (float*)(P +  190464);    //  160 f32
  u16*   wsComb   = (u16*)  (P +  191104);    //  15x1536 bf16
  u16*   wsHb     = (u16*)  (P +  237184);    //  15x768 bf16
  u16*   wsUpdB   = (u16*)  (P +  260224);    //  15x768 bf16
  u16*   wsActB   = (u16*)  (P +  283264);    //  5x32x768 bf16
  u16*   wsH1b    = (u16*)  (P +  529024);    //  160x768 bf16
  u16*   wsCat    = (u16*)  (P +  774784);    //  160x1536 bf16
  u16*   wsG1b    = (u16*)  (P + 1266304);    //  160x768 bf16
  float* Ppart    = (float*)(P + 1512064);    //  ~2 MB f32 partials

  float* outGO = (float*)d_out;
  float* outCG = outGO + 25165824;
  float* outSC = outGO + 25288704;

  // ---- conversions (one fused launch) ----
  k_cvt4<<<dim3(2048), dim3(256), 0, stream>>>(visual, visB, 3145728,
                                               text, textB, 393216,
                                               vWqkv, WqkvB, 221184,
                                               vWo, WoB, 73728);

  // ---- graph node-update chain (split-K task GEMMs) ----
  k_comb_si<<<dim3(NLL*NCC + 96), dim3(256), 0, stream>>>(gnode, gedge, wsComb, sentemb, wsSent);
  gemm_tk<16,0><<<dim3(144), dim3(256), 0, stream>>>(wsComb, gW1, Ppart,
      3, 8, 2*EE, 2*EE, (long)NCC*2*EE, (long)EE*2*EE);
  k_lnred<<<dim3(15), dim3(256), 0, stream>>>(Ppart, wsHb, gb1, EE, glng, glnb, EE,
      16, 3, 8, 5, 768, 3840);
  gemm_tk<16,0><<<dim3(72), dim3(256), 0, stream>>>(wsHb, gW2, Ppart,
      3, 4, EE, EE, (long)NCC*EE, (long)EE*EE);
  k_red<<<dim3(15), dim3(256), 0, stream>>>(Ppart, wsUpd, wsUpdB, gb2, EE,
      16, 3, 4, 5, 768, 3840);
  gemm_tk<16,0><<<dim3(72), dim3(256), 0, stream>>>(wsUpdB, gWqkv + (size_t)EE*EE, Ppart,
      3, 4, EE, EE, (long)NCC*EE, (long)3*EE*EE);
  k_red<<<dim3(15), dim3(256), 0, stream>>>(Ppart, wsKhg, nullptr, gbqkv + EE, (long)3*EE,
      16, 3, 4, 5, 768, 3840);

  // ---- sentence loop (l==2 absorbs actprep) ----
  for (int l=0;l<NLL;l++) {
    gemm_tk<32,1><<<dim3(48), dim3(256), 0, stream>>>(wsSent, gWqkv + (size_t)l*3*EE*EE, Ppart,
        1, 8, EE, EE, 0, 0);
    k_attn2<<<dim3(NB), dim3(256), 0, stream>>>(l, Ppart, gbqkv + (size_t)l*3*EE,
        presence, wsUpd, wsKhg, wsSent, wsScores,
        (l==NLL-1)?outSC:(float*)nullptr, wsActB, wsCat);
  }

  // ---- class guidance chain ----
  gemm_tk<32,0><<<dim3(120), dim3(256), 0, stream>>>(wsActB, cW1, Ppart,
      5, 4, EE, EE, (long)NB*EE, (long)EE*EE);
  k_lnred<<<dim3(160), dim3(256), 0, stream>>>(Ppart, wsH1b, cb1, EE, clng, clnb, EE,
      32, 5, 4, 32, 768, 24576);
  gemm_tk<32,0><<<dim3(120), dim3(256), 0, stream>>>(wsH1b, cW2, Ppart,
      5, 4, EE, EE, (long)NB*EE, (long)EE*EE);
  k_red<<<dim3(160), dim3(256), 0, stream>>>(Ppart, nullptr, wsCat, cb2, EE,
      32, 5, 4, 32, 7680, 1536);
  gemm_tk<32,0><<<dim3(120), dim3(256), 0, stream>>>(wsCat, gfW1, Ppart,
      5, 4, 2*EE, 2*EE, (long)NB*2*EE, 0);
  k_lnred<<<dim3(160), dim3(256), 0, stream>>>(Ppart, wsG1b, gfb1, 0, gflng, gflnb, 0,
      32, 5, 4, 32, 768, 24576);
  gemm_tk<32,0><<<dim3(120), dim3(256), 0, stream>>>(wsG1b, gfW2, Ppart,
      5, 4, EE, EE, (long)NB*EE, 0);
  k_red<<<dim3(160), dim3(256), 0, stream>>>(Ppart, outCG, nullptr, gfb2, 0,
      32, 5, 4, 32, 768, 24576);

  // ---- visual-text fusion (XCD-swizzled 1-D grids) ----
  gemm_bt<4,0><<<dim3(1536), dim3(256), 0, stream>>>(visB, WqkvB, vbqkv, nullptr,
                                                     wsQ, nullptr, nullptr, NB*PP, EE, EE, 6);
  gemm_bt<2,0><<<dim3(384), dim3(256), 0, stream>>>(textB, WqkvB + (size_t)EE*EE, vbqkv+EE, nullptr,
                                                    wsK, nullptr, wsVt, NB*SEQ, 2*EE, EE, 12);
  attn_k<<<dim3(2, HH, NB), dim3(256), 0, stream>>>(wsQ, wsK, wsVt);
  k_cvt<<<dim3(512), dim3(256), 0, stream>>>(outW, outWB, 73728);   // into dead wsK (d_ws)
  gemm_bt<1,1><<<dim3(1536), dim3(256), 0, stream>>>(wsQ, WoB, vbo, visB,
                                                     wsG, nullptr, nullptr, NB*PP, EE, EE, 6);
  k_ln<<<dim3(NB*PP), dim3(256), 0, stream>>>(wsG, normg, normb);
  gemm_bt<3,0><<<dim3(1536), dim3(256), 0, stream>>>(wsG, outWB, outb, nullptr,
                                                     nullptr, outGO, nullptr, NB*PP, EE, EE, 6);
}